// Round 1
// baseline (179.030 us; speedup 1.0000x reference)
//
#include <hip/hip_runtime.h>

#define N_NODES 100000
#define N_EDGES 1600000
#define F 16
#define EDGES_PER_BLOCK 256
#define FSLAB 260   // 16 k-cells * 16 i + 4 pad (keeps float4 16B alignment; 260 ≡ 4 mod 32 banks)

// Explicit zero kernel. Size is a COMPILE-TIME constant (N_NODES*F floats):
// the previous version computed n4 = out_size/4 assuming out_size was a float
// count; with out_size in BYTES that zeroed 25.6 MB from a 6.4 MB buffer — a
// 19.2 MB OOB write whose victim depends on allocator layout (explains
// pass-in-one-session / post-timing-divergence-in-another).
#define OUT_FLOAT4 ((N_NODES * F) / 4)   // 400000

__global__ __launch_bounds__(256) void zero_out_kernel(float4* __restrict__ out) {
    int i = blockIdx.x * 256 + threadIdx.x;
    if (i < OUT_FLOAT4) out[i] = make_float4(0.f, 0.f, 0.f, 0.f);
}

__global__ __launch_bounds__(256) void basis_conv_edges(
    const float* __restrict__ x,          // [N_NODES, 16]
    const int*   __restrict__ edge_index, // [2, N_EDGES]
    const float* __restrict__ edge_attr,  // [N_EDGES, 2]
    const float* __restrict__ weight,     // [4,4,16,16] row-major = [k][i][f]
    float*       __restrict__ out)        // [N_NODES, 16], zeroed by zero_out_kernel
{
    // LDS layout [f][k][i]: lane f reads 16 consecutive i-values per cell as 4x float4.
    __shared__ float wl[F * FSLAB];
    for (int idx = threadIdx.x; idx < 4096; idx += 256) {
        const int f = idx & 15;
        const int i = (idx >> 4) & 15;
        const int k = idx >> 8;
        wl[f * FSLAB + k * 16 + i] = weight[idx];
    }
    __syncthreads();

    const int f = threadIdx.x & 15;   // output feature handled by this lane
    const int s = threadIdx.x >> 4;   // edge slot within pass (0..15)
    const int ebase = blockIdx.x * EDGES_PER_BLOCK;

#pragma unroll 1
    for (int it = 0; it < EDGES_PER_BLOCK / 16; ++it) {
        const int e = ebase + it * 16 + s;

        const int row = edge_index[e];            // destination node
        const int col = edge_index[N_EDGES + e];  // source node
        const float2 attr = ((const float2*)edge_attr)[e];

        // hat basis, 4 centers on [-1,1], spacing 2/3: exactly 2 nonzero per dim
        float fu = (attr.x + 1.0f) * 1.5f;
        int iu = (int)fu; iu = iu < 0 ? 0 : (iu > 2 ? 2 : iu);
        const float wu1 = fu - (float)iu;
        const float wu0 = 1.0f - wu1;

        float fv = (attr.y + 1.0f) * 1.5f;
        int iv = (int)fv; iv = iv < 0 ? 0 : (iv > 2 ? 2 : iv);
        const float wv1 = fv - (float)iv;
        const float wv0 = 1.0f - wv1;

        const int k0 = iu * 4 + iv;
        int   kb[4];
        float tw[4];
        kb[0] = k0;     tw[0] = wu0 * wv0;
        kb[1] = k0 + 1; tw[1] = wu0 * wv1;
        kb[2] = k0 + 4; tw[2] = wu1 * wv0;
        kb[3] = k0 + 5; tw[3] = wu1 * wv1;

        // gather x_j: 16 lanes of this edge read the same 64B -> L1 broadcast
        const float4* xv = (const float4*)(x + (size_t)col * 16);
        float xs[16];
#pragma unroll
        for (int q = 0; q < 4; ++q) {
            float4 t4 = xv[q];
            xs[4 * q + 0] = t4.x; xs[4 * q + 1] = t4.y;
            xs[4 * q + 2] = t4.z; xs[4 * q + 3] = t4.w;
        }

        float msg = 0.0f;
#pragma unroll
        for (int p = 0; p < 4; ++p) {
            const float t = tw[p];
            const float4* wp = (const float4*)&wl[f * FSLAB + kb[p] * 16];
#pragma unroll
            for (int i4 = 0; i4 < 4; ++i4) {
                const float4 w = wp[i4];
                msg += t * (xs[4 * i4 + 0] * w.x + xs[4 * i4 + 1] * w.y +
                            xs[4 * i4 + 2] * w.z + xs[4 * i4 + 3] * w.w);
            }
        }

        // one atomic per lane; a wave covers 4 rows x 16 consecutive floats
        unsafeAtomicAdd(out + (size_t)row * 16 + f, msg);
    }
}

extern "C" void kernel_launch(void* const* d_in, const int* in_sizes, int n_in,
                              void* d_out, int out_size, void* d_ws, size_t ws_size,
                              hipStream_t stream) {
    const float* x  = (const float*)d_in[0];
    const int*   ei = (const int*)d_in[1];
    const float* ea = (const float*)d_in[2];
    const float* w  = (const float*)d_in[3];
    float* out = (float*)d_out;
    (void)out_size; (void)d_ws; (void)ws_size; (void)in_sizes; (void)n_in;

    zero_out_kernel<<<(OUT_FLOAT4 + 255) / 256, 256, 0, stream>>>((float4*)out);

    const int blocks = N_EDGES / EDGES_PER_BLOCK;  // 6250
    basis_conv_edges<<<blocks, 256, 0, stream>>>(x, ei, ea, w, out);
}

// Round 3
// 165.553 us; speedup vs baseline: 1.0814x; 1.0814x over previous
//
#include <hip/hip_runtime.h>

#define N_NODES 100000
#define N_EDGES 1600000
#define F 16

// 512 edges per block: 4 waves x 8 groups of 16 edges. 1.6M/512 = 3125 blocks.
#define EDGES_PER_BLOCK 512
#define GROUPS_PER_WAVE 8

#define OUT_FLOAT4 ((N_NODES * F) / 4)   // 400000

typedef __attribute__((ext_vector_type(8))) short bf16x8;  // 8 bf16 (4 VGPRs)
typedef __attribute__((ext_vector_type(4))) float f32x4;   // MFMA C/D

__global__ __launch_bounds__(256) void zero_out_kernel(float4* __restrict__ out) {
    int i = blockIdx.x * 256 + threadIdx.x;
    if (i < OUT_FLOAT4) out[i] = make_float4(0.f, 0.f, 0.f, 0.f);
}

// pack two f32 -> one dword of 2 bf16 (RNE), single instruction.
// (__builtin_bit_cast of __hip_bfloat162 doesn't compile on gfx950/ROCm —
//  the type isn't trivially copyable — and there is no cvt_pk builtin.)
__device__ __forceinline__ unsigned pk_bf16(float lo, float hi) {
    unsigned r;
    asm("v_cvt_pk_bf16_f32 %0, %1, %2" : "=v"(r) : "v"(lo), "v"(hi));
    return r;
}

// D[e][f] = sum_cells t[e][cell] * (x_j[e] . W[cell][:][f]) via 8x
// mfma_f32_16x16x32_bf16 over the K=256 basis-expanded input. Weights live in
// 32 VGPRs as B-fragments (loaded once) -> ZERO LDS traffic in the edge loop
// (previous version was LDS-throughput-bound: 6.55 GB of ds_read_b128 ~= 95us
//  + 29us of bank conflicts ~= the whole 115us kernel).
__global__ __launch_bounds__(256) void basis_conv_mfma(
    const float* __restrict__ x,          // [N_NODES, 16]
    const int*   __restrict__ edge_index, // [2, N_EDGES]
    const float* __restrict__ edge_attr,  // [N_EDGES, 2]
    const float* __restrict__ weight,     // [4,4,16,16] = [cell][i][f]
    float*       __restrict__ out)        // [N_NODES, 16], pre-zeroed
{
    const int lane = threadIdx.x & 63;
    const int wid  = threadIdx.x >> 6;
    const int e15  = lane & 15;        // A-row: edge within group
    const int fo   = lane & 15;        // B/D col: output feature
    const int c    = lane >> 4;        // K-chunk 0..3 within each MFMA
    const int hv   = c >> 1;           // 0: even cell of the pair, 1: odd cell
    const int i0   = (c & 1) * 8;      // input-feature offset within cell

    // --- B fragments (weights), loaded once. MFMA m covers cells 2m, 2m+1.
    // Lane element j: B[K][fo] with K = c*8 + j -> cell = 2m+hv, i = i0+j.
    bf16x8 bw[8];
#pragma unroll
    for (int m = 0; m < 8; ++m) {
        const float* wp = weight + (2 * m + hv) * 256 + i0 * 16 + fo;
        union { bf16x8 v; unsigned u[4]; } bb;
#pragma unroll
        for (int p = 0; p < 4; ++p)
            bb.u[p] = pk_bf16(wp[(2 * p) * 16], wp[(2 * p + 1) * 16]);
        bw[m] = bb.v;
    }

    const int wbase = blockIdx.x * EDGES_PER_BLOCK + wid * (16 * GROUPS_PER_WAVE);

#pragma unroll 1
    for (int g = 0; g < GROUPS_PER_WAVE; ++g) {
        const int eg = wbase + g * 16;

        // per-lane edge for the A side (4-way redundant across c -> L1 broadcast)
        const int col   = edge_index[N_EDGES + eg + e15];
        const float2 at = ((const float2*)edge_attr)[eg + e15];

        // hat basis, 4 centers on [-1,1]: exactly 2 adjacent nonzero per dim
        float fu = (at.x + 1.0f) * 1.5f;
        int iu = (int)fu; iu = iu < 0 ? 0 : (iu > 2 ? 2 : iu);
        const float wu1 = fu - (float)iu, wu0 = 1.0f - wu1;
        float fv = (at.y + 1.0f) * 1.5f;
        int iv = (int)fv; iv = iv < 0 ? 0 : (iv > 2 ? 2 : iv);
        const float wv1 = fv - (float)iv, wv0 = 1.0f - wv1;

        // 1D basis values at each center index
        const float bu0 = iu == 0 ? wu0 : 0.f;
        const float bu1 = iu == 0 ? wu1 : (iu == 1 ? wu0 : 0.f);
        const float bu2 = iu == 2 ? wu0 : (iu == 1 ? wu1 : 0.f);
        const float bu3 = iu == 2 ? wu1 : 0.f;
        const float bv0 = iv == 0 ? wv0 : 0.f;
        const float bv1 = iv == 0 ? wv1 : (iv == 1 ? wv0 : 0.f);
        const float bv2 = iv == 2 ? wv0 : (iv == 1 ? wv1 : 0.f);
        const float bv3 = iv == 2 ? wv1 : 0.f;

        // cell = 2m+hv: cu = m>>1 (compile-time per unrolled m); cv = (2m&3)|hv
        const float bvE = hv ? bv1 : bv0;  // m even
        const float bvO = hv ? bv3 : bv2;  // m odd

        // x_j slice for this lane's K-chunk (constant across all 8 MFMAs)
        const float4* xv = (const float4*)(x + (size_t)col * 16 + i0);
        const float4 xa = xv[0], xb = xv[1];

        // two independent accumulator chains (even/odd m) to halve MFMA latency chain
        f32x4 acc0 = {0.f, 0.f, 0.f, 0.f};
        f32x4 acc1 = {0.f, 0.f, 0.f, 0.f};
#pragma unroll
        for (int m = 0; m < 8; ++m) {
            const float bu = (m >> 1) == 0 ? bu0 : (m >> 1) == 1 ? bu1
                           : (m >> 1) == 2 ? bu2 : bu3;
            const float t = bu * ((m & 1) ? bvO : bvE);
            union { bf16x8 v; unsigned u[4]; } aa;
            aa.u[0] = pk_bf16(t * xa.x, t * xa.y);
            aa.u[1] = pk_bf16(t * xa.z, t * xa.w);
            aa.u[2] = pk_bf16(t * xb.x, t * xb.y);
            aa.u[3] = pk_bf16(t * xb.z, t * xb.w);
            if (m & 1)
                acc1 = __builtin_amdgcn_mfma_f32_16x16x32_bf16(aa.v, bw[m], acc1, 0, 0, 0);
            else
                acc0 = __builtin_amdgcn_mfma_f32_16x16x32_bf16(aa.v, bw[m], acc0, 0, 0, 0);
        }
        const f32x4 acc = acc0 + acc1;

        // D layout: row = c*4 + reg (edge in group), col = lane&15 (out feature)
        const int4 r4 = *(const int4*)(edge_index + eg + 4 * c);
        unsafeAtomicAdd(out + (size_t)r4.x * 16 + fo, acc.x);
        unsafeAtomicAdd(out + (size_t)r4.y * 16 + fo, acc.y);
        unsafeAtomicAdd(out + (size_t)r4.z * 16 + fo, acc.z);
        unsafeAtomicAdd(out + (size_t)r4.w * 16 + fo, acc.w);
    }
}

extern "C" void kernel_launch(void* const* d_in, const int* in_sizes, int n_in,
                              void* d_out, int out_size, void* d_ws, size_t ws_size,
                              hipStream_t stream) {
    const float* x  = (const float*)d_in[0];
    const int*   ei = (const int*)d_in[1];
    const float* ea = (const float*)d_in[2];
    const float* w  = (const float*)d_in[3];
    float* out = (float*)d_out;
    (void)out_size; (void)d_ws; (void)ws_size; (void)in_sizes; (void)n_in;

    zero_out_kernel<<<(OUT_FLOAT4 + 255) / 256, 256, 0, stream>>>((float4*)out);

    const int blocks = N_EDGES / EDGES_PER_BLOCK;  // 3125
    basis_conv_mfma<<<blocks, 256, 0, stream>>>(x, ei, ea, w, out);
}

// Round 4
// 162.116 us; speedup vs baseline: 1.1043x; 1.0212x over previous
//
#include <hip/hip_runtime.h>

#define N_NODES 100000
#define N_EDGES 1600000
#define F 16

// 512 edges per block: 4 waves x 8 groups of 16 edges. 1.6M/512 = 3125 blocks.
#define EDGES_PER_BLOCK 512
#define GROUPS_PER_WAVE 8

#define OUT_FLOAT4 ((N_NODES * F) / 4)   // 400000

typedef __attribute__((ext_vector_type(8))) short bf16x8;  // 8 bf16 (4 VGPRs)
typedef __attribute__((ext_vector_type(4))) float f32x4;   // MFMA C/D

__global__ __launch_bounds__(256) void zero_out_kernel(float4* __restrict__ out) {
    int i = blockIdx.x * 256 + threadIdx.x;
    if (i < OUT_FLOAT4) out[i] = make_float4(0.f, 0.f, 0.f, 0.f);
}

// pack two f32 -> one dword of 2 bf16 (RNE), single instruction.
__device__ __forceinline__ unsigned pk_bf16(float lo, float hi) {
    unsigned r;
    asm("v_cvt_pk_bf16_f32 %0, %1, %2" : "=v"(r) : "v"(lo), "v"(hi));
    return r;
}

// MFMA formulation (round 3): D[e][f] = sum over K=256 basis-expanded inputs,
// weights resident in 32 VGPRs as B-fragments, zero LDS. Round-3 counters
// showed all pipes idle (VALU 32%, MFMA 5.5%, HBM 23%, occ 29%) -> latency
// bound on the serial idx->x->compute chain. This version adds a 2-deep
// software pipeline: at iter g, issue x-load for g+1 (col known from last
// iter) and idx/attr/rows for g+2, then compute g. Loads get a full
// iteration to land; waitcnt for them sits after the atomics.
__global__ __launch_bounds__(256) void basis_conv_mfma(
    const float* __restrict__ x,          // [N_NODES, 16]
    const int*   __restrict__ edge_index, // [2, N_EDGES] (int32 on device)
    const float* __restrict__ edge_attr,  // [N_EDGES, 2]
    const float* __restrict__ weight,     // [4,4,16,16] = [cell][i][f]
    float*       __restrict__ out)        // [N_NODES, 16], pre-zeroed
{
    const int lane = threadIdx.x & 63;
    const int wid  = threadIdx.x >> 6;
    const int e15  = lane & 15;        // A-row: edge within group
    const int fo   = lane & 15;        // B/D col: output feature
    const int c    = lane >> 4;        // K-chunk 0..3 within each MFMA
    const int hv   = c >> 1;           // 0: even cell of the pair, 1: odd cell
    const int i0   = (c & 1) * 8;      // input-feature offset within cell

    // --- B fragments (weights), loaded once. MFMA m covers cells 2m, 2m+1.
    bf16x8 bw[8];
#pragma unroll
    for (int m = 0; m < 8; ++m) {
        const float* wp = weight + (2 * m + hv) * 256 + i0 * 16 + fo;
        union { bf16x8 v; unsigned u[4]; } bb;
#pragma unroll
        for (int p = 0; p < 4; ++p)
            bb.u[p] = pk_bf16(wp[(2 * p) * 16], wp[(2 * p + 1) * 16]);
        bw[m] = bb.v;
    }

    const int wbase = blockIdx.x * EDGES_PER_BLOCK + wid * (16 * GROUPS_PER_WAVE);

    // ---- 2-deep pipeline state ----
    int col0, col1; float2 at0, at1; int4 r40, r41;
    float4 xa0, xb0;
    {
        const int eg0 = wbase;
        col0 = edge_index[N_EDGES + eg0 + e15];
        at0  = ((const float2*)edge_attr)[eg0 + e15];
        r40  = *(const int4*)(edge_index + eg0 + 4 * c);
        const float4* xv = (const float4*)(x + (size_t)col0 * 16 + i0);
        xa0 = xv[0]; xb0 = xv[1];
        const int eg1 = wbase + 16;            // always < N_EDGES (wbase <= 1599872)
        col1 = edge_index[N_EDGES + eg1 + e15];
        at1  = ((const float2*)edge_attr)[eg1 + e15];
        r41  = *(const int4*)(edge_index + eg1 + 4 * c);
    }

#pragma unroll 1
    for (int g = 0; g < GROUPS_PER_WAVE; ++g) {
        // issue stage-1 x gather (col1 resident from previous iteration)
        const float4* xv1 = (const float4*)(x + (size_t)col1 * 16 + i0);
        const float4 xa1 = xv1[0], xb1 = xv1[1];

        // issue stage-2 idx/attr/rows (clamped: beyond-grid prefetch reads
        // valid neighbor edges; results unused on the last groups)
        int eg2 = wbase + (g + 2) * 16;
        eg2 = eg2 > (N_EDGES - 16) ? (N_EDGES - 16) : eg2;
        const int   col2 = edge_index[N_EDGES + eg2 + e15];
        const float2 at2 = ((const float2*)edge_attr)[eg2 + e15];
        const int4  r42  = *(const int4*)(edge_index + eg2 + 4 * c);

        // ---- compute on stage-0 (all operands already in registers) ----
        float fu = (at0.x + 1.0f) * 1.5f;
        int iu = (int)fu; iu = iu < 0 ? 0 : (iu > 2 ? 2 : iu);
        const float wu1 = fu - (float)iu, wu0 = 1.0f - wu1;
        float fv = (at0.y + 1.0f) * 1.5f;
        int iv = (int)fv; iv = iv < 0 ? 0 : (iv > 2 ? 2 : iv);
        const float wv1 = fv - (float)iv, wv0 = 1.0f - wv1;

        const float bu0 = iu == 0 ? wu0 : 0.f;
        const float bu1 = iu == 0 ? wu1 : (iu == 1 ? wu0 : 0.f);
        const float bu2 = iu == 2 ? wu0 : (iu == 1 ? wu1 : 0.f);
        const float bu3 = iu == 2 ? wu1 : 0.f;
        const float bv0 = iv == 0 ? wv0 : 0.f;
        const float bv1 = iv == 0 ? wv1 : (iv == 1 ? wv0 : 0.f);
        const float bv2 = iv == 2 ? wv0 : (iv == 1 ? wv1 : 0.f);
        const float bv3 = iv == 2 ? wv1 : 0.f;

        const float bvE = hv ? bv1 : bv0;  // m even
        const float bvO = hv ? bv3 : bv2;  // m odd

        f32x4 acc0 = {0.f, 0.f, 0.f, 0.f};
        f32x4 acc1 = {0.f, 0.f, 0.f, 0.f};
#pragma unroll
        for (int m = 0; m < 8; ++m) {
            const float bu = (m >> 1) == 0 ? bu0 : (m >> 1) == 1 ? bu1
                           : (m >> 1) == 2 ? bu2 : bu3;
            const float t = bu * ((m & 1) ? bvO : bvE);
            union { bf16x8 v; unsigned u[4]; } aa;
            aa.u[0] = pk_bf16(t * xa0.x, t * xa0.y);
            aa.u[1] = pk_bf16(t * xa0.z, t * xa0.w);
            aa.u[2] = pk_bf16(t * xb0.x, t * xb0.y);
            aa.u[3] = pk_bf16(t * xb0.z, t * xb0.w);
            if (m & 1)
                acc1 = __builtin_amdgcn_mfma_f32_16x16x32_bf16(aa.v, bw[m], acc1, 0, 0, 0);
            else
                acc0 = __builtin_amdgcn_mfma_f32_16x16x32_bf16(aa.v, bw[m], acc0, 0, 0, 0);
        }
        const f32x4 acc = acc0 + acc1;

        // D layout: row = c*4 + reg (edge in group), col = lane&15 (out feature)
        unsafeAtomicAdd(out + (size_t)r40.x * 16 + fo, acc.x);
        unsafeAtomicAdd(out + (size_t)r40.y * 16 + fo, acc.y);
        unsafeAtomicAdd(out + (size_t)r40.z * 16 + fo, acc.z);
        unsafeAtomicAdd(out + (size_t)r40.w * 16 + fo, acc.w);

        // ---- shift pipeline (waitcnt for the prefetch loads lands here,
        //      after a full iteration of latency cover) ----
        col0 = col1; at0 = at1; r40 = r41;
        xa0 = xa1;  xb0 = xb1;
        col1 = col2; at1 = at2; r41 = r42;
    }
}

extern "C" void kernel_launch(void* const* d_in, const int* in_sizes, int n_in,
                              void* d_out, int out_size, void* d_ws, size_t ws_size,
                              hipStream_t stream) {
    const float* x  = (const float*)d_in[0];
    const int*   ei = (const int*)d_in[1];
    const float* ea = (const float*)d_in[2];
    const float* w  = (const float*)d_in[3];
    float* out = (float*)d_out;
    (void)out_size; (void)d_ws; (void)ws_size; (void)in_sizes; (void)n_in;

    zero_out_kernel<<<(OUT_FLOAT4 + 255) / 256, 256, 0, stream>>>((float4*)out);

    const int blocks = N_EDGES / EDGES_PER_BLOCK;  // 3125
    basis_conv_mfma<<<blocks, 256, 0, stream>>>(x, ei, ea, w, out);
}